// Round 4
// baseline (376.601 us; speedup 1.0000x reference)
//
#include <hip/hip_runtime.h>

typedef _Float16 half_t;
typedef _Float16 half4 __attribute__((ext_vector_type(4)));
typedef _Float16 half8 __attribute__((ext_vector_type(8)));
typedef float floatx4 __attribute__((ext_vector_type(4)));

#define HST 264            // LDS row stride in halves: 256 + 8 pad
#define B_ 32
#define T_ 512
#define H_ 256
#define L_ 2048

// ------------------------------------------------------------------
// Fused setup: blocks [0,128) = meta (scan/searchsorted/bucket idx),
// blocks [128,512) = weight prep fp32 -> f16 MFMA fragment layout.
// Frag id t = ((pred*4+layer)*8 + kk)*16 + nt ; lane l holds 8 halves:
//   W[kk*32 + (l>>4)*8 + j][nt*16 + (l&15)]
// ------------------------------------------------------------------
__global__ __launch_bounds__(256) void setup_kernel(
    const int* __restrict__ dur,
    const float* __restrict__ pitch_t,
    const float* __restrict__ energy_t,
    const float* __restrict__ dur_W,
    const float* __restrict__ pit_W,
    const float* __restrict__ en_W,
    half_t* __restrict__ Wp,
    int* __restrict__ idx_ws,
    int* __restrict__ pi_ws,
    int* __restrict__ ei_ws,
    int* __restrict__ ml_ws,
    float* __restrict__ out4,
    float* __restrict__ out5) {
  __shared__ int cum_l[T_];
  __shared__ int ml_s;
  int bid = blockIdx.x;
  int tid = threadIdx.x;

  if (bid >= 128) {
    // ---- weight prep ----
    int g = (bid - 128) * 256 + tid;          // [0, 98304)
    int lane = g & 63;
    int t = g >> 6;                            // [0, 1536)
    int nt = t & 15;
    int kk = (t >> 4) & 7;
    int layer = (t >> 7) & 3;
    int pred = t >> 9;
    const float* W = (pred == 0 ? dur_W : (pred == 1 ? pit_W : en_W)) + layer * 65536;
    int n = nt * 16 + (lane & 15);
    int k0 = kk * 32 + (lane >> 4) * 8;
    half8 o;
#pragma unroll
    for (int j = 0; j < 8; ++j) o[j] = (half_t)W[(k0 + j) * 256 + n];
    *(half8*)&Wp[(size_t)t * 512 + lane * 8] = o;
    return;
  }

  // ---- meta ----
  int b = bid >> 2;
  int chunk = bid & 3;
  if (tid < 64) {
    int l = tid;
    const int* dr = dur + b * T_;
    int v[8];
    int base = l * 8;
#pragma unroll
    for (int j = 0; j < 8; ++j) v[j] = dr[base + j];
#pragma unroll
    for (int j = 1; j < 8; ++j) v[j] += v[j - 1];
    int tot = v[7];
    int inc = tot;
    for (int d = 1; d < 64; d <<= 1) {
      int t = __shfl_up(inc, d);
      if (l >= d) inc += t;
    }
    int excl = inc - tot;
#pragma unroll
    for (int j = 0; j < 8; ++j) cum_l[base + j] = excl + v[j];
    if (l == 63) {
      int mel = min(inc, L_);
      ml_s = mel;
      if (chunk == 0) {
        ml_ws[b] = mel;
        out4[b] = (float)mel;
      }
    }
  }
  __syncthreads();
  int ml = ml_s;
#pragma unroll
  for (int j = 0; j < 2; ++j) {
    int m = chunk * 512 + j * 256 + tid;
    int lo = 0;
#pragma unroll
    for (int sh = 8; sh >= 0; --sh) {
      int c = lo + (1 << sh);
      if (c <= T_ && cum_l[c - 1] <= m) lo = c;
    }
    int idx = min(lo, T_ - 1);
    int g = b * L_ + m;
    idx_ws[g] = idx;
    pi_ws[g] = (int)ceilf(pitch_t[g] * 256.0f);
    ei_ws[g] = (int)ceilf(energy_t[g] * 256.0f);
    out5[g] = (m >= ml) ? 1.0f : 0.0f;
  }
}

// ------------------------------------------------------------------
// Fused 4-layer MLP + head (round-0 proven structure + local deltas).
// blocks [0,1024): pitch  [1024,2048): energy  [2048,2304): duration.
// Block = 128 threads (2 waves) owning 64 rows; each wave owns 32
// rows EXCLUSIVELY -> zero __syncthreads. Each wave loops ALL 16 nt
// tiles; weight prefetch DISTANCE 2 via 3 rotating 8xhalf8 buffers
// (~156 cyc cover vs ~200 cyc L2 latency; layer-boundary loads issue
// before the hf LDS reloads for extra cover). LDS 33.8 KB -> 4
// blocks/CU -> 2 waves/SIMD; VGPR budget 256 via launch_bounds(128,2).
// Pitch-mode staging also emits out0 = xe + pemb + eemb (fused
// out0_kernel: same gather, nontemporal store).
// ------------------------------------------------------------------
#define LOADW(WB, BB, NT)                                                          \
  {                                                                                \
    _Pragma("unroll")                                                              \
    for (int kk = 0; kk < 8; ++kk)                                                 \
      WB[kk] = *(const half8*)&wl[(size_t)(kk * 16 + (NT)) * 512 + lane * 8];      \
    BB = *(const float4*)&bl[(NT) * 16 + qi * 4];                                  \
  }

#define COMP(WB, BB, NT)                                                           \
  {                                                                                \
    floatx4 acc0 = {BB.x, BB.y, BB.z, BB.w};                                       \
    floatx4 acc1 = acc0;                                                           \
    _Pragma("unroll")                                                              \
    for (int kk = 0; kk < 8; ++kk) {                                               \
      acc0 = __builtin_amdgcn_mfma_f32_16x16x32_f16(WB[kk], hf[0][kk], acc0, 0, 0, 0); \
      acc1 = __builtin_amdgcn_mfma_f32_16x16x32_f16(WB[kk], hf[1][kk], acc1, 0, 0, 0); \
    }                                                                              \
    int colbase = (NT) * 16 + qi * 4;                                              \
    half4 h40, h41;                                                                \
    h40[0] = (half_t)fmaxf(acc0[0], 0.f); h40[1] = (half_t)fmaxf(acc0[1], 0.f);    \
    h40[2] = (half_t)fmaxf(acc0[2], 0.f); h40[3] = (half_t)fmaxf(acc0[3], 0.f);    \
    h41[0] = (half_t)fmaxf(acc1[0], 0.f); h41[1] = (half_t)fmaxf(acc1[1], 0.f);    \
    h41[2] = (half_t)fmaxf(acc1[2], 0.f); h41[3] = (half_t)fmaxf(acc1[3], 0.f);    \
    *(half4*)&hlds[(wrow0 + mi) * HST + colbase] = h40;                            \
    *(half4*)&hlds[(wrow0 + 16 + mi) * HST + colbase] = h41;                       \
  }

__global__ __launch_bounds__(128, 2) void predictor_kernel(
    const float* __restrict__ x,
    const half_t* __restrict__ Wp,
    const float* __restrict__ dur_b, const float* __restrict__ dur_w, const float* __restrict__ dur_b2,
    const float* __restrict__ pit_b, const float* __restrict__ pit_w, const float* __restrict__ pit_b2,
    const float* __restrict__ en_b,  const float* __restrict__ en_w,  const float* __restrict__ en_b2,
    const int* __restrict__ idx_ws, const int* __restrict__ pi_ws, const int* __restrict__ ei_ws,
    const int* __restrict__ mlw,
    const float* __restrict__ src_seq, const unsigned char* __restrict__ src_mask,
    const float* __restrict__ pemb, const float* __restrict__ eemb,
    float* __restrict__ out0, float* __restrict__ out1,
    float* __restrict__ out2, float* __restrict__ out3) {
  __shared__ half_t hlds[64 * HST];
  int bid = blockIdx.x;
  int mode, blk;
  const half_t* W; const float* bias; const float* wh; const float* b2p; float* outp;
  if (bid < 1024)      { mode = 1; blk = bid;        W = Wp + 262144; bias = pit_b; wh = pit_w; b2p = pit_b2; outp = out2; }
  else if (bid < 2048) { mode = 2; blk = bid - 1024; W = Wp + 524288; bias = en_b;  wh = en_w;  b2p = en_b2;  outp = out3; }
  else                 { mode = 0; blk = bid - 2048; W = Wp;          bias = dur_b; wh = dur_w; b2p = dur_b2; outp = out1; }

  int tid = threadIdx.x;
  int wv = tid >> 6, lane = tid & 63;
  int mi = lane & 15, qi = lane >> 4;
  int wrow0 = wv * 32;            // wave's exclusive 32 rows within block
  int brow0 = blk * 64;

  // ---- stage this wave's 32 input rows (f16) into LDS ----
  if (mode == 0) {
    for (int it = 0; it < 32; ++it) {
      int rl = wrow0 + it;
      const float4 xv = *(const float4*)&x[(size_t)(brow0 + rl) * H_ + lane * 4];
      half4 h4;
      h4[0] = (half_t)xv.x; h4[1] = (half_t)xv.y;
      h4[2] = (half_t)xv.z; h4[3] = (half_t)xv.w;
      *(half4*)&hlds[rl * HST + lane * 4] = h4;
    }
  } else {
    int b = brow0 >> 11;          // 64 | 2048 frames per batch
    int m0 = brow0 & (L_ - 1);
    int ml = mlw[b];
    for (int it = 0; it < 32; ++it) {
      int rl = wrow0 + it;
      int m = m0 + rl;
      int g = b * L_ + m;
      float4 xv = {0.f, 0.f, 0.f, 0.f};
      if (m < ml) {
        int ir = idx_ws[g];
        xv = *(const float4*)&x[((size_t)(b * T_ + ir)) * H_ + lane * 4];
      }
      if (mode == 1) {
        // fused out0 = xe + pemb[pi] + eemb[ei]
        const float4 pv = *(const float4*)&pemb[(size_t)pi_ws[g] * H_ + lane * 4];
        const float4 ev = *(const float4*)&eemb[(size_t)ei_ws[g] * H_ + lane * 4];
        floatx4 o;
        o[0] = xv.x + pv.x + ev.x;
        o[1] = xv.y + pv.y + ev.y;
        o[2] = xv.z + pv.z + ev.z;
        o[3] = xv.w + pv.w + ev.w;
        __builtin_nontemporal_store(o, (floatx4*)&out0[(size_t)g * H_ + lane * 4]);
      }
      half4 h4;
      h4[0] = (half_t)xv.x; h4[1] = (half_t)xv.y;
      h4[2] = (half_t)xv.z; h4[3] = (half_t)xv.w;
      *(half4*)&hlds[rl * HST + lane * 4] = h4;
    }
  }
  // no barrier: wave-exclusive rows

  half8 w0[8], w1[8], w2[8];
  float4 b0, b1, b2v;

  // ---- 4 layers: h = relu(h @ W + b), in-place per wave ----
#pragma unroll 1
  for (int layer = 0; layer < 4; ++layer) {
    const half_t* wl = W + (size_t)layer * 65536;
    const float* bl = bias + layer * 256;

    // issue first two weight chunks, then hf LDS reads cover their latency
    LOADW(w0, b0, 0);
    LOADW(w1, b1, 1);

    // wave's 32 rows' fragments into registers (64 VGPRs)
    half8 hf[2][8];   // [mt][kk] : h[wrow0+mt*16+mi][kk*32+qi*8 .. +7]
#pragma unroll
    for (int mt = 0; mt < 2; ++mt)
#pragma unroll
      for (int kk = 0; kk < 8; ++kk)
        hf[mt][kk] = *(const half8*)&hlds[(wrow0 + mt * 16 + mi) * HST + kk * 32 + qi * 8];

    // distance-2 pipelined nt loop (buffer for chunk c is w[c%3])
    LOADW(w2, b2v, 2);  COMP(w0, b0, 0);
    LOADW(w0, b0, 3);   COMP(w1, b1, 1);
    LOADW(w1, b1, 4);   COMP(w2, b2v, 2);
    LOADW(w2, b2v, 5);  COMP(w0, b0, 3);
    LOADW(w0, b0, 6);   COMP(w1, b1, 4);
    LOADW(w1, b1, 7);   COMP(w2, b2v, 5);
    LOADW(w2, b2v, 8);  COMP(w0, b0, 6);
    LOADW(w0, b0, 9);   COMP(w1, b1, 7);
    LOADW(w1, b1, 10);  COMP(w2, b2v, 8);
    LOADW(w2, b2v, 11); COMP(w0, b0, 9);
    LOADW(w0, b0, 12);  COMP(w1, b1, 10);
    LOADW(w1, b1, 13);  COMP(w2, b2v, 11);
    LOADW(w2, b2v, 14); COMP(w0, b0, 12);
    LOADW(w0, b0, 15);  COMP(w1, b1, 13);
    COMP(w2, b2v, 14);
    COMP(w0, b0, 15);
  }

  // ---- head: out = h . w + b2, per-mode epilogue. 2 lanes per row ----
  {
    int r = lane >> 1, hf2 = lane & 1;
    int rl = wrow0 + r;
    float sum = 0.f;
    const half_t* hrow = &hlds[rl * HST + hf2 * 128];
    const float* whp = wh + hf2 * 128;
#pragma unroll
    for (int j = 0; j < 16; ++j) {
      half8 hv = *(const half8*)&hrow[j * 8];
#pragma unroll
      for (int u = 0; u < 8; ++u) sum += (float)hv[u] * whp[j * 8 + u];
    }
    sum += __shfl_xor(sum, 1);
    if (hf2 == 0) {
      int row = brow0 + rl;
      float d = sum + b2p[0];
      if (mode == 0) {
        if (src_mask[row]) d = 0.f;
        float s2 = src_seq[(size_t)row * 3 + 2];
        outp[row] = (tanhf(d) + 1.0f) * s2;
      } else {
        int b = row >> 11;
        int m = row & (L_ - 1);
        float v = (m >= mlw[b]) ? 0.f : d;
        outp[row] = (mode == 1) ? fmaxf(v, 0.f) : v;
      }
    }
  }
}

extern "C" void kernel_launch(void* const* d_in, const int* in_sizes, int n_in,
                              void* d_out, int out_size, void* d_ws, size_t ws_size,
                              hipStream_t stream) {
  const float* x        = (const float*)d_in[0];
  const float* src_seq  = (const float*)d_in[1];
  const int*   durt     = (const int*)d_in[2];
  const float* pitcht   = (const float*)d_in[3];
  const float* energyt  = (const float*)d_in[4];
  const unsigned char* src_mask = (const unsigned char*)d_in[5];
  const float* dur_W  = (const float*)d_in[7];
  const float* dur_b  = (const float*)d_in[8];
  const float* dur_w  = (const float*)d_in[9];
  const float* dur_b2 = (const float*)d_in[10];
  const float* pit_W  = (const float*)d_in[11];
  const float* pit_b  = (const float*)d_in[12];
  const float* pit_w  = (const float*)d_in[13];
  const float* pit_b2 = (const float*)d_in[14];
  const float* en_W   = (const float*)d_in[15];
  const float* en_b   = (const float*)d_in[16];
  const float* en_w   = (const float*)d_in[17];
  const float* en_b2  = (const float*)d_in[18];
  const float* pemb   = (const float*)d_in[19];
  const float* eemb   = (const float*)d_in[20];

  float* out0 = (float*)d_out;              // [32,2048,256]
  float* out1 = out0 + 16777216;            // [32,512]   log_duration
  float* out2 = out1 + 16384;               // [32,2048]  pitch_prediction
  float* out3 = out2 + 65536;               // [32,2048]  energy_prediction
  float* out4 = out3 + 65536;               // [32]       mel_len (as float)
  float* out5 = out4 + 32;                  // [32,2048]  mel_mask (0/1 float)

  int* idx_ws = (int*)d_ws;                 // 65536 ints
  int* pi_ws  = idx_ws + 65536;             // 65536 ints
  int* ei_ws  = pi_ws + 65536;              // 65536 ints
  int* ml_ws  = ei_ws + 65536;              // 32 ints
  half_t* Wp  = (half_t*)((char*)d_ws + 786560);  // 786432 halves, 16B aligned

  setup_kernel<<<dim3(512), dim3(256), 0, stream>>>(
      durt, pitcht, energyt, dur_W, pit_W, en_W, Wp,
      idx_ws, pi_ws, ei_ws, ml_ws, out4, out5);
  predictor_kernel<<<dim3(2304), dim3(128), 0, stream>>>(
      x, Wp,
      dur_b, dur_w, dur_b2,
      pit_b, pit_w, pit_b2,
      en_b, en_w, en_b2,
      idx_ws, pi_ws, ei_ws, ml_ws, src_seq, src_mask, pemb, eemb,
      out0, out1, out2, out3);
}

// Round 5
// 277.989 us; speedup vs baseline: 1.3547x; 1.3547x over previous
//
#include <hip/hip_runtime.h>

typedef _Float16 half_t;
typedef _Float16 half4 __attribute__((ext_vector_type(4)));
typedef _Float16 half8 __attribute__((ext_vector_type(8)));
typedef float floatx4 __attribute__((ext_vector_type(4)));

#define HST 264            // LDS row stride in halves: 256 + 8 pad
#define B_ 32
#define T_ 512
#define H_ 256
#define L_ 2048

// ------------------------------------------------------------------
// Fused setup: blocks [0,128) = meta (scan/searchsorted/bucket idx),
// blocks [128,512) = weight prep fp32 -> f16, CHUNK-CONTIGUOUS layout:
//   chunk c = (pred*4+layer)*16 + nt   (8 KB each, linear for LDS DMA)
//   within chunk: halves [kk*512 + lane*8 .. +7] hold
//   W[kk*32 + (lane>>4)*8 + j][nt*16 + (lane&15)]
// ------------------------------------------------------------------
__global__ __launch_bounds__(256) void setup_kernel(
    const int* __restrict__ dur,
    const float* __restrict__ pitch_t,
    const float* __restrict__ energy_t,
    const float* __restrict__ dur_W,
    const float* __restrict__ pit_W,
    const float* __restrict__ en_W,
    half_t* __restrict__ Wp,
    int* __restrict__ idx_ws,
    int* __restrict__ pi_ws,
    int* __restrict__ ei_ws,
    int* __restrict__ ml_ws,
    float* __restrict__ out4,
    float* __restrict__ out5) {
  __shared__ int cum_l[T_];
  __shared__ int ml_s;
  int bid = blockIdx.x;
  int tid = threadIdx.x;

  if (bid >= 128) {
    // ---- weight prep ----
    int g = (bid - 128) * 256 + tid;          // [0, 98304)
    int lane = g & 63;
    int t = g >> 6;                            // [0, 1536)
    int nt = t & 15;
    int kk = (t >> 4) & 7;
    int layer = (t >> 7) & 3;
    int pred = t >> 9;
    const float* W = (pred == 0 ? dur_W : (pred == 1 ? pit_W : en_W)) + layer * 65536;
    int n = nt * 16 + (lane & 15);
    int k0 = kk * 32 + (lane >> 4) * 8;
    half8 o;
#pragma unroll
    for (int j = 0; j < 8; ++j) o[j] = (half_t)W[(k0 + j) * 256 + n];
    int c = (pred * 4 + layer) * 16 + nt;
    *(half8*)&Wp[(size_t)c * 4096 + kk * 512 + lane * 8] = o;
    return;
  }

  // ---- meta ----
  int b = bid >> 2;
  int chunk = bid & 3;
  if (tid < 64) {
    int l = tid;
    const int* dr = dur + b * T_;
    int v[8];
    int base = l * 8;
#pragma unroll
    for (int j = 0; j < 8; ++j) v[j] = dr[base + j];
#pragma unroll
    for (int j = 1; j < 8; ++j) v[j] += v[j - 1];
    int tot = v[7];
    int inc = tot;
    for (int d = 1; d < 64; d <<= 1) {
      int t = __shfl_up(inc, d);
      if (l >= d) inc += t;
    }
    int excl = inc - tot;
#pragma unroll
    for (int j = 0; j < 8; ++j) cum_l[base + j] = excl + v[j];
    if (l == 63) {
      int mel = min(inc, L_);
      ml_s = mel;
      if (chunk == 0) {
        ml_ws[b] = mel;
        out4[b] = (float)mel;
      }
    }
  }
  __syncthreads();
  int ml = ml_s;
#pragma unroll
  for (int j = 0; j < 2; ++j) {
    int m = chunk * 512 + j * 256 + tid;
    int lo = 0;
#pragma unroll
    for (int sh = 8; sh >= 0; --sh) {
      int c = lo + (1 << sh);
      if (c <= T_ && cum_l[c - 1] <= m) lo = c;
    }
    int idx = min(lo, T_ - 1);
    int g = b * L_ + m;
    idx_ws[g] = idx;
    pi_ws[g] = (int)ceilf(pitch_t[g] * 256.0f);
    ei_ws[g] = (int)ceilf(energy_t[g] * 256.0f);
    out5[g] = (m >= ml) ? 1.0f : 0.0f;
  }
}

// ------------------------------------------------------------------
// Fused 4-layer MLP + head.
// blocks [0,1024): pitch  [1024,2048): energy  [2048,2304): duration.
// Block = 128 threads (2 waves) / 64 rows; wave owns 32 rows
// EXCLUSIVELY (h in-place in LDS, no h hazards across waves).
// Weights: both waves share ONE LDS copy per 8 KB nt-chunk, staged
// with global_load_lds (zero VGPR for in-flight data), double-buffered.
// T3-minimal 2-phase per chunk:
//   STAGE(c+1) -> ds_read w[8] from buf[c&1] -> 16 MFMA + epilogue
//   -> __syncthreads (vmcnt drain covers loads issued ~310 cyc ago).
// Chunk is MFMA-pipe-bound (16 x ~19.4 cyc/SIMD) > ds_read 96 + VALU 60.
// LDS 33.8 (h) + 16 (wbuf) = 50.2 KB -> 3 blocks/CU -> 6 waves/CU.
// Pitch-mode staging also emits out0 = xe + pemb + eemb (fused).
// ------------------------------------------------------------------
__device__ __forceinline__ void stage16(const void* g, void* l) {
  __builtin_amdgcn_global_load_lds(
      (const __attribute__((address_space(1))) void*)g,
      (__attribute__((address_space(3))) void*)l, 16, 0, 0);
}

__global__ __launch_bounds__(128, 2) void predictor_kernel(
    const float* __restrict__ x,
    const half_t* __restrict__ Wp,
    const float* __restrict__ dur_b, const float* __restrict__ dur_w, const float* __restrict__ dur_b2,
    const float* __restrict__ pit_b, const float* __restrict__ pit_w, const float* __restrict__ pit_b2,
    const float* __restrict__ en_b,  const float* __restrict__ en_w,  const float* __restrict__ en_b2,
    const int* __restrict__ idx_ws, const int* __restrict__ pi_ws, const int* __restrict__ ei_ws,
    const int* __restrict__ mlw,
    const float* __restrict__ src_seq, const unsigned char* __restrict__ src_mask,
    const float* __restrict__ pemb, const float* __restrict__ eemb,
    float* __restrict__ out0, float* __restrict__ out1,
    float* __restrict__ out2, float* __restrict__ out3) {
  __shared__ half_t hlds[64 * HST];     // 33792 B: h tile, in-place per layer
  __shared__ half_t wldsw[8192];        // 16384 B: 2 x 8 KB weight chunk buffers

  int bid = blockIdx.x;
  int mode, blk;
  const half_t* W; const float* bias; const float* wh; const float* b2p; float* outp;
  if (bid < 1024)      { mode = 1; blk = bid;        W = Wp + 262144; bias = pit_b; wh = pit_w; b2p = pit_b2; outp = out2; }
  else if (bid < 2048) { mode = 2; blk = bid - 1024; W = Wp + 524288; bias = en_b;  wh = en_w;  b2p = en_b2;  outp = out3; }
  else                 { mode = 0; blk = bid - 2048; W = Wp;          bias = dur_b; wh = dur_w; b2p = dur_b2; outp = out1; }

  int tid = threadIdx.x;
  int wv = tid >> 6, lane = tid & 63;
  int mi = lane & 15, qi = lane >> 4;
  int wrow0 = wv * 32;            // wave's exclusive 32 rows within block
  int brow0 = blk * 64;

  const char* Wb = (const char*)W;          // chunk c at byte offset c*8192
  char* wbb = (char*)&wldsw[0];

  // stage chunk c into buf (c&1); wave wv covers the odd/even KBs.
#define STAGE(c)                                                        \
  {                                                                     \
    const char* gsrc = Wb + (size_t)(c) * 8192 + wv * 1024 + lane * 16; \
    char* ldst = wbb + ((c) & 1) * 8192 + wv * 1024;                    \
    stage16(gsrc,        ldst);                                         \
    stage16(gsrc + 2048, ldst + 2048);                                  \
    stage16(gsrc + 4096, ldst + 4096);                                  \
    stage16(gsrc + 6144, ldst + 6144);                                  \
  }

  // ---- issue chunk 0 stage first: lands under the h-gather below ----
  STAGE(0);

  // ---- stage this wave's 32 input rows (f16) into LDS ----
  if (mode == 0) {
    for (int it = 0; it < 32; ++it) {
      int rl = wrow0 + it;
      const float4 xv = *(const float4*)&x[(size_t)(brow0 + rl) * H_ + lane * 4];
      half4 h4;
      h4[0] = (half_t)xv.x; h4[1] = (half_t)xv.y;
      h4[2] = (half_t)xv.z; h4[3] = (half_t)xv.w;
      *(half4*)&hlds[rl * HST + lane * 4] = h4;
    }
  } else {
    int b = brow0 >> 11;          // 64 | 2048 frames per batch
    int m0 = brow0 & (L_ - 1);
    int ml = mlw[b];
    for (int it = 0; it < 32; ++it) {
      int rl = wrow0 + it;
      int m = m0 + rl;
      int g = b * L_ + m;
      float4 xv = {0.f, 0.f, 0.f, 0.f};
      if (m < ml) {
        int ir = idx_ws[g];
        xv = *(const float4*)&x[((size_t)(b * T_ + ir)) * H_ + lane * 4];
      }
      if (mode == 1) {
        // fused out0 = xe + pemb[pi] + eemb[ei]
        const float4 pv = *(const float4*)&pemb[(size_t)pi_ws[g] * H_ + lane * 4];
        const float4 ev = *(const float4*)&eemb[(size_t)ei_ws[g] * H_ + lane * 4];
        floatx4 o;
        o[0] = xv.x + pv.x + ev.x;
        o[1] = xv.y + pv.y + ev.y;
        o[2] = xv.z + pv.z + ev.z;
        o[3] = xv.w + pv.w + ev.w;
        __builtin_nontemporal_store(o, (floatx4*)&out0[(size_t)g * H_ + lane * 4]);
      }
      half4 h4;
      h4[0] = (half_t)xv.x; h4[1] = (half_t)xv.y;
      h4[2] = (half_t)xv.z; h4[3] = (half_t)xv.w;
      *(half4*)&hlds[rl * HST + lane * 4] = h4;
    }
  }
  __syncthreads();   // h ready (all waves), chunk 0 staged (vmcnt drained)

  // ---- 4 layers: h = relu(h @ W + b), in-place per wave ----
#pragma unroll 1
  for (int layer = 0; layer < 4; ++layer) {
    const float* bl = bias + layer * 256;

    // wave's 32 rows' fragments into registers (64 VGPRs)
    half8 hf[2][8];   // [mt][kk] : h[wrow0+mt*16+mi][kk*32+qi*8 .. +7]
#pragma unroll
    for (int mt = 0; mt < 2; ++mt)
#pragma unroll
      for (int kk = 0; kk < 8; ++kk)
        hf[mt][kk] = *(const half8*)&hlds[(wrow0 + mt * 16 + mi) * HST + kk * 32 + qi * 8];

#pragma unroll 2
    for (int nt = 0; nt < 16; ++nt) {
      int c = layer * 16 + nt;
      // issue next chunk's stage BEFORE this chunk's compute: its L2
      // latency hides under ~310 cyc of MFMA; the vmcnt(0) drain at the
      // __syncthreads below is then nearly free.
      if (c < 63) STAGE(c + 1);

      const half_t* wb = &wldsw[(c & 1) * 4096];
      half8 w[8];
#pragma unroll
      for (int kk = 0; kk < 8; ++kk)
        w[kk] = *(const half8*)&wb[kk * 512 + lane * 8];

      floatx4 acc0 = {0.f, 0.f, 0.f, 0.f};
      floatx4 acc1 = {0.f, 0.f, 0.f, 0.f};
#pragma unroll
      for (int kk = 0; kk < 8; ++kk) {
        acc0 = __builtin_amdgcn_mfma_f32_16x16x32_f16(w[kk], hf[0][kk], acc0, 0, 0, 0);
        acc1 = __builtin_amdgcn_mfma_f32_16x16x32_f16(w[kk], hf[1][kk], acc1, 0, 0, 0);
      }
      const float4 bv = *(const float4*)&bl[nt * 16 + qi * 4];
      int colbase = nt * 16 + qi * 4;
      half4 h40, h41;
      h40[0] = (half_t)fmaxf(acc0[0] + bv.x, 0.f);
      h40[1] = (half_t)fmaxf(acc0[1] + bv.y, 0.f);
      h40[2] = (half_t)fmaxf(acc0[2] + bv.z, 0.f);
      h40[3] = (half_t)fmaxf(acc0[3] + bv.w, 0.f);
      h41[0] = (half_t)fmaxf(acc1[0] + bv.x, 0.f);
      h41[1] = (half_t)fmaxf(acc1[1] + bv.y, 0.f);
      h41[2] = (half_t)fmaxf(acc1[2] + bv.z, 0.f);
      h41[3] = (half_t)fmaxf(acc1[3] + bv.w, 0.f);
      *(half4*)&hlds[(wrow0 + mi) * HST + colbase] = h40;
      *(half4*)&hlds[(wrow0 + 16 + mi) * HST + colbase] = h41;

      __syncthreads();   // chunk c consumed by both waves; chunk c+1 ready
    }
  }

  // ---- head: out = h . w + b2, per-mode epilogue. 2 lanes per row ----
  {
    int r = lane >> 1, hf2 = lane & 1;
    int rl = wrow0 + r;
    float sum = 0.f;
    const half_t* hrow = &hlds[rl * HST + hf2 * 128];
    const float* whp = wh + hf2 * 128;
#pragma unroll
    for (int j = 0; j < 16; ++j) {
      half8 hv = *(const half8*)&hrow[j * 8];
#pragma unroll
      for (int u = 0; u < 8; ++u) sum += (float)hv[u] * whp[j * 8 + u];
    }
    sum += __shfl_xor(sum, 1);
    if (hf2 == 0) {
      int row = brow0 + rl;
      float d = sum + b2p[0];
      if (mode == 0) {
        if (src_mask[row]) d = 0.f;
        float s2 = src_seq[(size_t)row * 3 + 2];
        outp[row] = (tanhf(d) + 1.0f) * s2;
      } else {
        int b = row >> 11;
        int m = row & (L_ - 1);
        float v = (m >= mlw[b]) ? 0.f : d;
        outp[row] = (mode == 1) ? fmaxf(v, 0.f) : v;
      }
    }
  }
#undef STAGE
}

extern "C" void kernel_launch(void* const* d_in, const int* in_sizes, int n_in,
                              void* d_out, int out_size, void* d_ws, size_t ws_size,
                              hipStream_t stream) {
  const float* x        = (const float*)d_in[0];
  const float* src_seq  = (const float*)d_in[1];
  const int*   durt     = (const int*)d_in[2];
  const float* pitcht   = (const float*)d_in[3];
  const float* energyt  = (const float*)d_in[4];
  const unsigned char* src_mask = (const unsigned char*)d_in[5];
  const float* dur_W  = (const float*)d_in[7];
  const float* dur_b  = (const float*)d_in[8];
  const float* dur_w  = (const float*)d_in[9];
  const float* dur_b2 = (const float*)d_in[10];
  const float* pit_W  = (const float*)d_in[11];
  const float* pit_b  = (const float*)d_in[12];
  const float* pit_w  = (const float*)d_in[13];
  const float* pit_b2 = (const float*)d_in[14];
  const float* en_W   = (const float*)d_in[15];
  const float* en_b   = (const float*)d_in[16];
  const float* en_w   = (const float*)d_in[17];
  const float* en_b2  = (const float*)d_in[18];
  const float* pemb   = (const float*)d_in[19];
  const float* eemb   = (const float*)d_in[20];

  float* out0 = (float*)d_out;              // [32,2048,256]
  float* out1 = out0 + 16777216;            // [32,512]   log_duration
  float* out2 = out1 + 16384;               // [32,2048]  pitch_prediction
  float* out3 = out2 + 65536;               // [32,2048]  energy_prediction
  float* out4 = out3 + 65536;               // [32]       mel_len (as float)
  float* out5 = out4 + 32;                  // [32,2048]  mel_mask (0/1 float)

  int* idx_ws = (int*)d_ws;                 // 65536 ints
  int* pi_ws  = idx_ws + 65536;             // 65536 ints
  int* ei_ws  = pi_ws + 65536;              // 65536 ints
  int* ml_ws  = ei_ws + 65536;              // 32 ints
  half_t* Wp  = (half_t*)((char*)d_ws + 786560);  // 786432 halves, 16B aligned

  setup_kernel<<<dim3(512), dim3(256), 0, stream>>>(
      durt, pitcht, energyt, dur_W, pit_W, en_W, Wp,
      idx_ws, pi_ws, ei_ws, ml_ws, out4, out5);
  predictor_kernel<<<dim3(2304), dim3(128), 0, stream>>>(
      x, Wp,
      dur_b, dur_w, dur_b2,
      pit_b, pit_w, pit_b2,
      en_b, en_w, en_b2,
      idx_ws, pi_ws, ei_ws, ml_ws, src_seq, src_mask, pemb, eemb,
      out0, out1, out2, out3);
}